// Round 12
// baseline (610.250 us; speedup 1.0000x reference)
//
#include <hip/hip_runtime.h>

// VQ-VAE codebook quantization — R12: LDS-free screen (scalar-load codebook).
// x: (4096, 1024) f32; codebook: (128, 256, 8) f32.
// out = [cw_embed (4096*1024 f32) | one_hot (4096*128*256 f32)].
//
// R11 post-mortem: R8's screen issues 768 LDS instrs/wave on the single
// per-CU LDS pipe (~61us at 16 waves/CU) — the best match for the ~50us of
// controllable time above the 91us write floor. (R9's counter-evidence was
// confounded: it also halved store-stream parallelism.) R12 removes LDS from
// the k-loop entirely: codebook addresses are wave-uniform (c=blockIdx,
// k=loop counter) -> scalar s_load path (SMEM/const cache); c2 recomputed
// in-loop with the IDENTICAL fmaf chain (bit-equal to the old LDS c2).
// No __syncthreads anywhere. Grid/stores byte-identical to R8 (best=582).
// Screen + fp64 repair numerics bit-identical to R2-R11 (absmax 0.0).

constexpr int B_  = 4096;
constexpr int C_  = 128;
constexpr int K_  = 256;
constexpr int D_  = 8;
constexpr int TPB = 256;

constexpr int   BPT   = 2;           // pairs per thread
constexpr int   BTILE = TPB * BPT;   // 512 b per block
constexpr float TAU2  = 1.0e-3f;     // ambiguity gap threshold

typedef float vf4 __attribute__((ext_vector_type(4)));

__global__ __launch_bounds__(TPB) void vq_fused(
    const float* __restrict__ x,
    const float* __restrict__ cb,
    float* __restrict__ out_embed,
    float* __restrict__ out_onehot)
{
    const int c    = blockIdx.x;   // 0..127
    const int bt   = blockIdx.y;   // 0..7
    const int tid  = threadIdx.x;
    const int lane = tid & 63;
    const int wave = tid >> 6;

    // wave-uniform codebook base for this c (reads scalarize to s_load)
    const float* __restrict__ cbc = cb + (size_t)c * (K_ * D_);

    const int bbase = bt * BTILE;

    // ---- x fragments ----
    float xf[BPT][D_];
    #pragma unroll
    for (int j = 0; j < BPT; ++j) {
        const int b = bbase + j * TPB + tid;
        const float4* xp = (const float4*)(x + (size_t)b * (C_ * D_) + c * D_);
        const float4 a = xp[0];
        const float4 h = xp[1];
        xf[j][0] = a.x; xf[j][1] = a.y; xf[j][2] = a.z; xf[j][3] = a.w;
        xf[j][4] = h.x; xf[j][5] = h.y; xf[j][6] = h.z; xf[j][7] = h.w;
    }

    // ---- fp32 top-2 screen (codebook via uniform scalar loads) ----
    float s1[BPT], s2[BPT];
    int   k1[BPT];
    #pragma unroll
    for (int j = 0; j < BPT; ++j) { s1[j] = 3.4e38f; s2[j] = 3.4e38f; k1[j] = 0; }

    #pragma unroll 4
    for (int k = 0; k < K_; ++k) {
        float cv[D_];
        #pragma unroll
        for (int d = 0; d < D_; ++d) cv[d] = cbc[k * D_ + d];  // uniform -> s_load
        // c2k: identical fmaf chain to the old LDS-staged version (bit-equal)
        float c2k = 0.f;
        #pragma unroll
        for (int d = 0; d < D_; ++d) c2k = fmaf(cv[d], cv[d], c2k);

        #pragma unroll
        for (int j = 0; j < BPT; ++j) {
            float dot = xf[j][0] * cv[0];
            dot = fmaf(xf[j][1], cv[1], dot);
            dot = fmaf(xf[j][2], cv[2], dot);
            dot = fmaf(xf[j][3], cv[3], dot);
            dot = fmaf(xf[j][4], cv[4], dot);
            dot = fmaf(xf[j][5], cv[5], dot);
            dot = fmaf(xf[j][6], cv[6], dot);
            dot = fmaf(xf[j][7], cv[7], dot);
            const float score = fmaf(-2.f, dot, c2k);
            // top-2 (s2 uses OLD s1; strict < keeps first-index winner)
            s2[j] = fminf(s2[j], fmaxf(score, s1[j]));
            const bool lt = score < s1[j];
            k1[j] = lt ? k : k1[j];
            s1[j] = lt ? score : s1[j];
        }
    }

    // ---- inline fp64 repair of ambiguous pairs (wave-cooperative) ----
    // (double) of the same f32 codebook values -> argmin matches np exactly.
    #pragma unroll
    for (int j = 0; j < BPT; ++j) {
        const bool amb = (s2[j] - s1[j]) <= TAU2;
        unsigned long long mask = __ballot(amb);
        while (mask) {
            const int src = (int)__ffsll((long long)mask) - 1;
            mask &= mask - 1;
            double xd[D_];
            #pragma unroll
            for (int d = 0; d < D_; ++d) xd[d] = (double)__shfl(xf[j][d], src);
            double best = 1.0e300;
            int    bk   = 0;
            #pragma unroll
            for (int t = 0; t < 4; ++t) {
                const int k = lane * 4 + t;      // ascending k within lane
                const float* cv = cbc + k * D_;  // per-lane, L1/L2-hot
                double cd[D_];
                #pragma unroll
                for (int d = 0; d < D_; ++d) cd[d] = (double)cv[d];
                double c2k = 0.0;
                #pragma unroll
                for (int d = 0; d < D_; ++d) c2k = fma(cd[d], cd[d], c2k);
                double dot = xd[0] * cd[0];
                #pragma unroll
                for (int d = 1; d < D_; ++d) dot = fma(xd[d], cd[d], dot);
                const double score = fma(-2.0, dot, c2k);
                if (score < best) { best = score; bk = k; }  // first-min
            }
            #pragma unroll
            for (int off = 32; off >= 1; off >>= 1) {
                const double ob  = __shfl_down(best, off);
                const int    obk = __shfl_down(bk,   off);
                if (ob < best) { best = ob; bk = obk; }  // tie -> lower k
            }
            const int win = __shfl(bk, 0);
            if (lane == src) k1[j] = win;
        }
    }

    // ---- writes (cached; identical structure to R8) ----
    #pragma unroll
    for (int j = 0; j < BPT; ++j) {
        // embed: own pair, 32B gathered from the L2-hot codebook
        const int    b    = bbase + j * TPB + tid;
        const size_t pair = (size_t)b * C_ + c;
        const vf4* src = (const vf4*)(cbc + k1[j] * D_);
        vf4* dst = (vf4*)(out_embed + pair * D_);
        dst[0] = src[0];
        dst[1] = src[1];

        // one-hot: wave writes its 64 lanes' rows; 1KB contiguous per instr
        const int bw = bbase + j * TPB + wave * 64;
        const int e0 = lane * 4;
        #pragma unroll 8
        for (int i = 0; i < 64; ++i) {
            const int k = __builtin_amdgcn_readlane(k1[j], i);
            vf4 v;
            v.x = (k == e0    ) ? 1.f : 0.f;
            v.y = (k == e0 + 1) ? 1.f : 0.f;
            v.z = (k == e0 + 2) ? 1.f : 0.f;
            v.w = (k == e0 + 3) ? 1.f : 0.f;
            const size_t row = (size_t)(bw + i) * C_ + c;
            ((vf4*)(out_onehot + row * K_))[lane] = v;
        }
    }
}

extern "C" void kernel_launch(void* const* d_in, const int* in_sizes, int n_in,
                              void* d_out, int out_size, void* d_ws, size_t ws_size,
                              hipStream_t stream) {
    const float* x  = (const float*)d_in[0];
    const float* cb = (const float*)d_in[1];
    float* out        = (float*)d_out;
    float* out_embed  = out;                          // 4096*1024
    float* out_onehot = out + (size_t)B_ * C_ * D_;   // 4096*128*256

    dim3 grid(C_, B_ / BTILE);  // (128, 8) = 1024 blocks, 4 per CU
    vq_fused<<<grid, TPB, 0, stream>>>(x, cb, out_embed, out_onehot);
}

// Round 13
// 581.120 us; speedup vs baseline: 1.0501x; 1.0501x over previous
//
#include <hip/hip_runtime.h>

// VQ-VAE codebook quantization — FINAL: revert to R8 (best measured: 582us).
// x: (4096, 1024) f32; codebook: (128, 256, 8) f32.
// out = [cw_embed (4096*1024 f32) | one_hot (4096*128*256 f32)].
//
// Design: single fused kernel. Block = (c, 512 b), 4 blocks/CU. Codebook
// slice (8KB) + c2 staged in LDS. fp32 top-2 screen; ambiguous pairs
// (gap<=1e-3, ~few %) repaired inline by a wave-cooperative fp64 re-argmin
// (exact vs numpy: absmax 0.0 across R2-R12). One-hot written as full-wave
// 1KB contiguous cached bursts; embed as 32B cached stores (L2 merges).
//
// Experiment matrix (R3-R12): cached>NT stores (-13us), 4 blocks/CU helps;
// LDS amortization, scalar-load screen, per-j interleave, sequential-stream
// writer, two-kernel split all neutral or regressions. dur_us is dominated
// by ~440us of harness poison-fills (rocprof); kernel part ~142us vs ~91us
// pure-write floor -> write-bound plateau, residual headroom < noise.

constexpr int B_  = 4096;
constexpr int C_  = 128;
constexpr int K_  = 256;
constexpr int D_  = 8;
constexpr int TPB = 256;

constexpr int   BPT   = 2;           // pairs per thread
constexpr int   BTILE = TPB * BPT;   // 512 b per block
constexpr float TAU2  = 1.0e-3f;     // ambiguity gap threshold

typedef float vf4 __attribute__((ext_vector_type(4)));

__global__ __launch_bounds__(TPB) void vq_fused(
    const float* __restrict__ x,
    const float* __restrict__ cb,
    float* __restrict__ out_embed,
    float* __restrict__ out_onehot)
{
    __shared__ float s_cbf[K_ * D_];  // 8 KB fp32 codebook slice
    __shared__ float s_c2f[K_];       // 1 KB fp32 ||c_k||^2

    const int c    = blockIdx.x;   // 0..127
    const int bt   = blockIdx.y;   // 0..7
    const int tid  = threadIdx.x;
    const int lane = tid & 63;
    const int wave = tid >> 6;

    // ---- stage codebook slice + c2 ----
    {
        const float4* gcb = (const float4*)(cb + (size_t)c * (K_ * D_));
        ((float4*)s_cbf)[tid]       = gcb[tid];
        ((float4*)s_cbf)[tid + TPB] = gcb[tid + TPB];
    }
    __syncthreads();
    {
        const float* v = s_cbf + tid * D_;
        float s = 0.f;
        #pragma unroll
        for (int d = 0; d < D_; ++d) s = fmaf(v[d], v[d], s);
        s_c2f[tid] = s;
    }
    __syncthreads();
    // LDS read-only below; k1 lives in registers — no more barriers.

    const float4* scb4 = (const float4*)s_cbf;
    const int bbase = bt * BTILE;

    // ---- x fragments ----
    float xf[BPT][D_];
    #pragma unroll
    for (int j = 0; j < BPT; ++j) {
        const int b = bbase + j * TPB + tid;
        const float4* xp = (const float4*)(x + (size_t)b * (C_ * D_) + c * D_);
        const float4 a = xp[0];
        const float4 h = xp[1];
        xf[j][0] = a.x; xf[j][1] = a.y; xf[j][2] = a.z; xf[j][3] = a.w;
        xf[j][4] = h.x; xf[j][5] = h.y; xf[j][6] = h.z; xf[j][7] = h.w;
    }

    // ---- fp32 top-2 screen ----
    float s1[BPT], s2[BPT];
    int   k1[BPT];
    #pragma unroll
    for (int j = 0; j < BPT; ++j) { s1[j] = 3.4e38f; s2[j] = 3.4e38f; k1[j] = 0; }

    #pragma unroll 2
    for (int k = 0; k < K_; ++k) {
        const float4 clo = scb4[k * 2];
        const float4 chi = scb4[k * 2 + 1];
        const float  c2k = s_c2f[k];
        #pragma unroll
        for (int j = 0; j < BPT; ++j) {
            float dot = xf[j][0] * clo.x;
            dot = fmaf(xf[j][1], clo.y, dot);
            dot = fmaf(xf[j][2], clo.z, dot);
            dot = fmaf(xf[j][3], clo.w, dot);
            dot = fmaf(xf[j][4], chi.x, dot);
            dot = fmaf(xf[j][5], chi.y, dot);
            dot = fmaf(xf[j][6], chi.z, dot);
            dot = fmaf(xf[j][7], chi.w, dot);
            const float score = fmaf(-2.f, dot, c2k);
            // top-2 (s2 uses OLD s1; strict < keeps first-index winner)
            s2[j] = fminf(s2[j], fmaxf(score, s1[j]));
            const bool lt = score < s1[j];
            k1[j] = lt ? k : k1[j];
            s1[j] = lt ? score : s1[j];
        }
    }

    // ---- inline fp64 repair of ambiguous pairs (wave-cooperative) ----
    // (double)f32 from LDS == R2's exact staging -> argmin matches np.
    #pragma unroll
    for (int j = 0; j < BPT; ++j) {
        const bool amb = (s2[j] - s1[j]) <= TAU2;
        unsigned long long mask = __ballot(amb);
        while (mask) {
            const int src = (int)__ffsll((long long)mask) - 1;
            mask &= mask - 1;
            double xd[D_];
            #pragma unroll
            for (int d = 0; d < D_; ++d) xd[d] = (double)__shfl(xf[j][d], src);
            double best = 1.0e300;
            int    bk   = 0;
            #pragma unroll
            for (int t = 0; t < 4; ++t) {
                const int k = lane * 4 + t;      // ascending k within lane
                const float* cv = s_cbf + k * D_;
                double cd[D_];
                #pragma unroll
                for (int d = 0; d < D_; ++d) cd[d] = (double)cv[d];
                double c2k = 0.0;
                #pragma unroll
                for (int d = 0; d < D_; ++d) c2k = fma(cd[d], cd[d], c2k);
                double dot = xd[0] * cd[0];
                #pragma unroll
                for (int d = 1; d < D_; ++d) dot = fma(xd[d], cd[d], dot);
                const double score = fma(-2.0, dot, c2k);
                if (score < best) { best = score; bk = k; }  // first-min
            }
            #pragma unroll
            for (int off = 32; off >= 1; off >>= 1) {
                const double ob  = __shfl_down(best, off);
                const int    obk = __shfl_down(bk,   off);
                if (ob < best) { best = ob; bk = obk; }  // tie -> lower k
            }
            const int win = __shfl(bk, 0);
            if (lane == src) k1[j] = win;
        }
    }

    // ---- writes (cached; full lines per 8 lanes, no RMW on one-hot) ----
    #pragma unroll
    for (int j = 0; j < BPT; ++j) {
        // embed: own pair, 32B from LDS slice; L2 merges half-lines across
        // adjacent-c blocks (cached stores).
        const int    b    = bbase + j * TPB + tid;
        const size_t pair = (size_t)b * C_ + c;
        float4* dst = (float4*)(out_embed + pair * D_);
        dst[0] = ((const float4*)s_cbf)[k1[j] * 2];
        dst[1] = ((const float4*)s_cbf)[k1[j] * 2 + 1];

        // one-hot: wave writes its 64 lanes' rows; each store instruction is
        // one contiguous 1KB burst (16 full lines).
        const int bw = bbase + j * TPB + wave * 64;
        const int e0 = lane * 4;
        #pragma unroll 8
        for (int i = 0; i < 64; ++i) {
            const int k = __builtin_amdgcn_readlane(k1[j], i);
            vf4 v;
            v.x = (k == e0    ) ? 1.f : 0.f;
            v.y = (k == e0 + 1) ? 1.f : 0.f;
            v.z = (k == e0 + 2) ? 1.f : 0.f;
            v.w = (k == e0 + 3) ? 1.f : 0.f;
            const size_t row = (size_t)(bw + i) * C_ + c;
            ((vf4*)(out_onehot + row * K_))[lane] = v;
        }
    }
}

extern "C" void kernel_launch(void* const* d_in, const int* in_sizes, int n_in,
                              void* d_out, int out_size, void* d_ws, size_t ws_size,
                              hipStream_t stream) {
    const float* x  = (const float*)d_in[0];
    const float* cb = (const float*)d_in[1];
    float* out        = (float*)d_out;
    float* out_embed  = out;                          // 4096*1024
    float* out_onehot = out + (size_t)B_ * C_ * D_;   // 4096*128*256

    dim3 grid(C_, B_ / BTILE);  // (128, 8) = 1024 blocks, 4 per CU
    vq_fused<<<grid, TPB, 0, stream>>>(x, cb, out_embed, out_onehot);
}